// Round 11
// baseline (406.260 us; speedup 1.0000x reference)
//
#include <hip/hip_runtime.h>
#include <hip/hip_bf16.h>
#include <math.h>

#define DIN 128
#define DH  128
#define DC  40

#define NSTRIPE 256
#define NPAD    50176          // padded node slots (196 * 256)
#define H8_WORDS (NPAD / 4)    // u8-packed histogram words = 12544
#define LROW    392            // LDS AG row stride in u16 (384 + 8 pad: 2-way banks)

typedef unsigned short u16;
typedef unsigned int u32;
typedef unsigned char u8;
typedef __attribute__((ext_vector_type(2))) float f32x2;
typedef __attribute__((ext_vector_type(4))) float f32x4;
typedef __attribute__((ext_vector_type(8))) short bf16x8;

static __device__ __forceinline__ float bf2f(u16 u) {
    union { u32 i; float f; } v; v.i = ((u32)u) << 16; return v.f;
}
static __device__ __forceinline__ u16 f2bf(float f) {
    __hip_bfloat16 h = __float2bfloat16(f);
    union { __hip_bfloat16 h; u16 u; } v; v.h = h; return v.u;
}
static __device__ __forceinline__ u32 pack2bf(float a, float b) {
    return ((u32)f2bf(b) << 16) | (u32)f2bf(a);
}
// 1-inst packed f32->bf16 pair (lo = a, hi = b); RNE, matches __float2bfloat16
static __device__ __forceinline__ u32 cvtpk_bf16(float a, float b) {
    u32 r;
    asm("v_cvt_pk_bf16_f32 %0, %1, %2" : "=v"(r) : "v"(a), "v"(b));
    return r;
}

// ---------- fp8 e4m3fn helpers ----------
static __device__ __forceinline__ u8 f2fp8(float f) {
    u32 s = (__float_as_uint(f) >> 31) << 7;
    float a = fabsf(f);
    a = fminf(a, 448.f);
    if (a < 0.015625f) {
        int q = (int)rintf(a * 512.f);
        return (u8)(s | (u32)q);
    }
    u32 x = __float_as_uint(a);
    u32 lsb = (x >> 20) & 1;
    x += 0x0007FFFF + lsb;
    u32 e = (x >> 23) - 120;
    u32 m = (x >> 20) & 7;
    return (u8)(s | (e << 3) | m);
}

#if __has_builtin(__builtin_amdgcn_cvt_pk_f32_fp8)
template<bool HI>
static __device__ __forceinline__ f32x2 fp8pk(u32 w) {
    return __builtin_amdgcn_cvt_pk_f32_fp8((int)w, HI);
}
#else
static __device__ __forceinline__ float fp8dec1(u32 byte) {
    u32 s = (byte >> 7) & 1, em = byte & 0x7F;
    float v = __uint_as_float((s << 31) | (em << 20)) * 0x1p120f;
    return v;
}
template<bool HI>
static __device__ __forceinline__ f32x2 fp8pk(u32 w) {
    u32 b0 = HI ? ((w >> 16) & 0xff) : (w & 0xff);
    u32 b1 = HI ? ((w >> 24) & 0xff) : ((w >> 8) & 0xff);
    f32x2 r; r.x = fp8dec1(b0); r.y = fp8dec1(b1); return r;
}
#endif

// ---------- fused weight prep: w1 frags + w2 frags + attn dots + biases
// ---------- + zero rows of Xq/h8 (for guard-free aggregation) ----------
__global__ __launch_bounds__(256) void k_prep(
        const float* w11s, const float* w11n, const float* w12, const float* w13,
        const float* b11, const float* b12, const float* b13, const float* cw1,
        const float* w21s, const float* w21n, const float* w22, const float* w23,
        const float* b21, const float* b22, const float* b23, const float* cw2,
        const float* a13l, const float* a13r, const float* a23l, const float* a23r,
        u16* __restrict__ Wf1, u16* __restrict__ Wf2,
        float* __restrict__ bc1, float* __restrict__ bc2, float* __restrict__ vattn,
        u32* __restrict__ zq, u32* __restrict__ zh) {
    int i = blockIdx.x * 256 + threadIdx.x;
    float s1 = cw1[0] + cw1[1] + cw1[2];
    float u0 = cw1[0] / s1, u1 = cw1[1] / s1, u2 = cw1[2] / s1;
    float s2 = cw2[0] + cw2[1] + cw2[2];
    float q0 = cw2[0] / s2, q1 = cw2[1] / s2, q2 = cw2[2] / s2;
    if (i < 65536) {                                   // Wf1 frags
        int j = i & 7, lane = (i >> 3) & 63, nt = (i >> 9) & 7, kt = i >> 12;
        int k = kt * 32 + ((lane >> 4) << 3) + j;
        int n = nt * 16 + (lane & 15);
        float v;
        if (k < 128)      v = u0 * w11s[k * 128 + n];
        else if (k < 256) v = u0 * w11n[(k - 128) * 128 + n];
        else if (k < 384) v = u1 * w12[(k - 256) * 128 + n];
        else              v = u2 * w13[(k - 384) * 128 + n];
        Wf1[i] = f2bf(v);
    } else if (i < 90112) {                            // Wf2 frags
        int i2 = i - 65536;
        int j = i2 & 7;
        int l2 = i2 >> 3;
        int lane = l2 & 63;
        int t2 = l2 >> 6;
        int nt = t2 % 3, kt = t2 / 3;
        int k = kt * 32 + ((lane >> 4) << 3) + j;
        int n = nt * 16 + (lane & 15);
        float v = 0.f;
        if (n < 40) {
            if (k < 128)      v = q0 * w21s[k * 40 + n];
            else if (k < 256) v = q0 * w21n[(k - 128) * 40 + n];
            else if (k < 384) v = q1 * w22[(k - 256) * 40 + n];
            else              v = q2 * w23[(k - 384) * 40 + n];
        }
        Wf2[i2] = f2bf(v);
    } else if (i < 90624) {                            // attn dots
        int t = i - 90112;
        if (t < 128) {
            float s = 0; for (int j = 0; j < 128; ++j) s += w13[t * 128 + j] * a13l[j];
            vattn[t] = s;
        } else if (t < 256) {
            int r = t - 128; float s = 0; for (int j = 0; j < 128; ++j) s += w13[r * 128 + j] * a13r[j];
            vattn[t] = s;
        } else if (t < 384) {
            int r = t - 256; float s = 0; for (int j = 0; j < 40; ++j) s += w23[r * 40 + j] * a23l[j];
            vattn[t] = s;
        } else {
            int r = t - 384; float s = 0; for (int j = 0; j < 40; ++j) s += w23[r * 40 + j] * a23r[j];
            vattn[t] = s;
        }
    } else if (i < 90752) {                            // bc1
        int c = i - 90624;
        bc1[c] = u0 * b11[c] + u1 * b12[c] + u2 * b13[c];
    } else if (i < 90792) {                            // bc2
        int c = i - 90752;
        bc2[c] = q0 * b21[c] + q1 * b22[c] + q2 * b23[c];
    } else if (i < 90856) {                            // zero rows Xq[n], h8[n]
        int t = i - 90792;
        if (t < 32) zq[t] = 0u; else zh[t - 32] = 0u;
    }
}

// ---------- CSR build: single-chunk dual LDS histogram, ONE edge pass ----------
__global__ __launch_bounds__(1024) void k_hist2(const int* __restrict__ src,
        const int* __restrict__ dst,
        u8* __restrict__ partialsS, u8* __restrict__ partialsD,
        u8* __restrict__ wsrank, int E, int eps) {
    __shared__ u32 histD[H8_WORDS];
    __shared__ u32 histS[H8_WORDS];
    int stripe = blockIdx.x;
    for (int i = threadIdx.x; i < H8_WORDS; i += 1024) { histD[i] = 0; histS[i] = 0; }
    __syncthreads();
    int e0 = stripe * eps;
    int e1 = e0 + eps; if (e1 > E) e1 = E;
    for (int e = e0 + threadIdx.x; e < e1; e += 1024) {
        int ks = src[e];
        int kd = dst[e];
        atomicAdd(&histS[ks >> 2], 1u << ((ks & 3) * 8));
        u32 old = atomicAdd(&histD[kd >> 2], 1u << ((kd & 3) * 8));
        wsrank[e] = (u8)((old >> ((kd & 3) * 8)) & 0xff);
    }
    __syncthreads();
    u32* prowS = (u32*)(partialsS + (size_t)stripe * NPAD);
    u32* prowD = (u32*)(partialsD + (size_t)stripe * NPAD);
    for (int i = threadIdx.x; i < H8_WORDS; i += 1024) { prowD[i] = histD[i]; prowS[i] = histS[i]; }
}

// per-node: src totals -> ns; dst prefix in place (u8) -> indeg; fused block-scan
__global__ __launch_bounds__(256) void k_pfx2(const u8* __restrict__ partialsS,
        u8* __restrict__ partialsD,
        int* __restrict__ excl, int* __restrict__ bsum,
        float* __restrict__ ns, int n) {
    int node = blockIdx.x * 256 + threadIdx.x;
    int runS = 0;
    for (int s0 = 0; s0 < NSTRIPE; s0 += 16) {
        u8 c[16];
#pragma unroll
        for (int i = 0; i < 16; ++i) c[i] = partialsS[(size_t)(s0 + i) * NPAD + node];
#pragma unroll
        for (int i = 0; i < 16; ++i) runS += c[i];
    }
    int runD = 0;
    for (int s0 = 0; s0 < NSTRIPE; s0 += 16) {
        u8 c[16];
#pragma unroll
        for (int i = 0; i < 16; ++i) c[i] = partialsD[(size_t)(s0 + i) * NPAD + node];
#pragma unroll
        for (int i = 0; i < 16; ++i) {
            partialsD[(size_t)(s0 + i) * NPAD + node] = (u8)runD;
            runD += c[i];
        }
    }
    if (node < n) {
        int d = runS < 1 ? 1 : runS;
        ns[node] = rsqrtf((float)d);
    }
    __shared__ int sh[256];
    sh[threadIdx.x] = runD; __syncthreads();
    for (int o = 1; o < 256; o <<= 1) {
        int t = (threadIdx.x >= o) ? sh[threadIdx.x - o] : 0;
        __syncthreads(); sh[threadIdx.x] += t; __syncthreads();
    }
    excl[node] = sh[threadIdx.x] - runD;
    if (threadIdx.x == 255) bsum[blockIdx.x] = sh[255];
}

// atomic-free placement: rowptr + stripe-prefix (u8) + within-stripe rank (u8)
__global__ __launch_bounds__(256) void k_place2(const int* __restrict__ src,
        const int* __restrict__ dst, const int* __restrict__ rowptr,
        const u8* __restrict__ partials, const u8* __restrict__ wsrank,
        int* __restrict__ col, int E, int eps) {
    int stripe = blockIdx.x;
    const u8* prow = partials + (size_t)stripe * NPAD;
    int sub = (eps + 3) >> 2;
    int e0 = stripe * eps + blockIdx.y * sub;
    int e1 = e0 + sub;
    int cap = stripe * eps + eps; if (cap > E) cap = E;
    if (e1 > cap) e1 = cap;
    for (int e = e0 + threadIdx.x; e < e1; e += 256) {
        int d = dst[e];
        col[rowptr[d] + prow[d] + wsrank[e]] = src[e];
    }
}

// ---------- fused: f32 x -> bf16 Xb + fp8 Xq + logits + rowptr finalize ----------
__global__ __launch_bounds__(256) void k_cvt_dots(const float* __restrict__ X,
        const float* __restrict__ vl, const float* __restrict__ vr, const float* __restrict__ ns,
        const int* __restrict__ excl, const int* __restrict__ bsum,
        u16* __restrict__ Xb, u8* __restrict__ Xq,
        float2* __restrict__ elns, float* __restrict__ er,
        int* __restrict__ rowptr, int n, int E, int pb) {
    __shared__ int sh[256], shE[256];
    int t = threadIdx.x;
    int v = (t < pb) ? bsum[t] : 0;
    sh[t] = v; __syncthreads();
    for (int o = 1; o < 256; o <<= 1) {
        int u = (t >= o) ? sh[t - o] : 0;
        __syncthreads(); sh[t] += u; __syncthreads();
    }
    shE[t] = sh[t] - v;        // exclusive scan of block sums
    __syncthreads();
    if (blockIdx.x == 0 && t == 0) rowptr[n] = E;
    int w = (blockIdx.x * blockDim.x + t) >> 6;
    int lane = t & 63;
    if (w >= n) return;
    float2 xv = *(const float2*)&X[(size_t)w * 128 + lane * 2];
    *(u32*)&Xb[(size_t)w * 128 + lane * 2] = cvtpk_bf16(xv.x, xv.y);
    u16 q = (u16)f2fp8(xv.x) | ((u16)f2fp8(xv.y) << 8);
    *(u16*)&Xq[(size_t)w * 128 + lane * 2] = q;
    float2 a = *(const float2*)&vl[lane * 2];
    float2 b = *(const float2*)&vr[lane * 2];
    float dl = xv.x * a.x + xv.y * a.y;
    float dr = xv.x * b.x + xv.y * b.y;
    for (int off = 32; off; off >>= 1) {
        dl += __shfl_down(dl, off);
        dr += __shfl_down(dr, off);
    }
    if (lane == 0) {
        rowptr[w] = excl[w] + shE[w >> 8];
        elns[w] = make_float2(dl, ns[w]);
        er[w] = dr;
    }
}

// ---------- per-wave 4-node aggregation tile -> LDS row (proven round-7 form) ----------
// Group g owns node w; writes its full 384-col AG row into LDS at dstRow.
// Inactive (w >= n): all accumulators 0 -> writes zeros (row safe for MFMA).
static __device__ __forceinline__ void agg_tile(const u8* __restrict__ F,
        const int* __restrict__ rowptr, const int* __restrict__ colsrc,
        const float2* __restrict__ elns, const float* __restrict__ er,
        int n, int w, int g, int gl, u16* __restrict__ dstRow) {
    bool act = (w < n);
    int beg = 0, end = 0;
    if (act) { beg = rowptr[w]; end = rowptr[w + 1]; }
    int k = end - beg;
    float erd = act ? er[w] : 0.f;
    int kmax = k;
    kmax = max(kmax, __shfl_xor(kmax, 16));
    kmax = max(kmax, __shfl_xor(kmax, 32));
    f32x2 aS2[4] = {}, aG2[4] = {}, aA2[4] = {};
    float ssum_l = 0.f;
    for (int c = 0; c < kmax; c += 16) {
        int cnt = k - c; cnt = cnt < 0 ? 0 : (cnt > 16 ? 16 : cnt);
        int s = n; float p = 0.f, nsl = 0.f;
        if (gl < cnt) {
            s = colsrc[beg + c + gl];
            float2 v = elns[s];
            float t = v.x + erd;
            t = t > 0.f ? t : 0.2f * t;            // leaky_relu 0.2
            p = __expf(t);
            nsl = v.y;
        }
        ssum_l += p;
        int cm = kmax - c; if (cm > 16) cm = 16;   // wave-uniform step bound
#pragma unroll 8
        for (int t = 0; t < cm; ++t) {
            int j = (g << 4) + t;                  // edge t of MY group
            int sj = __shfl(s, j);
            float pj = __shfl(p, j);
            float nsj = __shfl(nsl, j);
            uint2 xq = *(const uint2*)&F[(size_t)sj * 128 + gl * 8];
            f32x2 xv2[4] = {fp8pk<false>(xq.x), fp8pk<true>(xq.x),
                            fp8pk<false>(xq.y), fp8pk<true>(xq.y)};
            f32x2 ns2 = {nsj, nsj}, pw = {pj, pj};
#pragma unroll
            for (int q = 0; q < 4; ++q) {
                aS2[q] += xv2[q];
                aG2[q] += ns2 * xv2[q];
                aA2[q] += pw * xv2[q];
            }
        }
    }
    ssum_l += __shfl_xor(ssum_l, 1);
    ssum_l += __shfl_xor(ssum_l, 2);
    ssum_l += __shfl_xor(ssum_l, 4);
    ssum_l += __shfl_xor(ssum_l, 8);
    int kc = k < 1 ? 1 : k;
    float invk = 1.f / (float)kc;
    float ndd = rsqrtf((float)kc);
    float gi = 1.f / fmaxf(ssum_l, 1e-9f);
    *(uint4*)&dstRow[gl * 8] = make_uint4(
        pack2bf(aS2[0][0] * invk, aS2[0][1] * invk), pack2bf(aS2[1][0] * invk, aS2[1][1] * invk),
        pack2bf(aS2[2][0] * invk, aS2[2][1] * invk), pack2bf(aS2[3][0] * invk, aS2[3][1] * invk));
    *(uint4*)&dstRow[128 + gl * 8] = make_uint4(
        pack2bf(aG2[0][0] * ndd, aG2[0][1] * ndd), pack2bf(aG2[1][0] * ndd, aG2[1][1] * ndd),
        pack2bf(aG2[2][0] * ndd, aG2[2][1] * ndd), pack2bf(aG2[3][0] * ndd, aG2[3][1] * ndd));
    *(uint4*)&dstRow[256 + gl * 8] = make_uint4(
        pack2bf(aA2[0][0] * gi, aA2[0][1] * gi), pack2bf(aA2[1][0] * gi, aA2[1][1] * gi),
        pack2bf(aA2[2][0] * gi, aA2[2][1] * gi), pack2bf(aA2[3][0] * gi, aA2[3][1] * gi));
}

// ---------- FUSED layer1: aggregate 64 nodes -> LDS, then MFMA GEMM + BN partials ----------
// 512 threads (8 waves). AG never touches HBM (saves 76.8 MB round-trip).
// Gemm phase: wave v = row-quarter (v&3) x tile-half (v>>2); A from Xb(global)/AG(LDS).
__global__ __launch_bounds__(512) void k_aggemm1(const u8* __restrict__ Xq,
        const int* __restrict__ rowptr, const int* __restrict__ colsrc,
        const float2* __restrict__ elns, const float* __restrict__ er,
        const u16* __restrict__ Xb, const u16* __restrict__ Wf,
        const float* __restrict__ bias, u16* __restrict__ C,
        float* __restrict__ bnpart, int M) {
    __shared__ u16 AGs[64 * LROW];                // 49 KB, +8-pad -> 2-way banks
    __shared__ float sS[128], sQ[128];
    int tid = threadIdx.x;
    int v = tid >> 6;
    int lane = tid & 63;
    int g = lane >> 4, gl = lane & 15;
    int m0 = blockIdx.x * 64;
    // agg phase: wave v -> local rows v*8 .. v*8+7 (2 passes of 4 nodes)
#pragma unroll
    for (int it = 0; it < 2; ++it) {
        int lw = v * 8 + it * 4 + g;
        agg_tile(Xq, rowptr, colsrc, elns, er, M, m0 + lw, g, gl, &AGs[lw * LROW]);
    }
    if (tid < 128) { sS[tid] = 0.f; sQ[tid] = 0.f; }
    __syncthreads();
    // gemm phase
    int rq = v & 3, nh = v >> 2;
    int lr = rq * 16 + (lane & 15);
    int arow = m0 + lr;
    if (arow >= M) arow = M - 1;
    int kq = lane >> 4;
    f32x4 acc[4];
#pragma unroll
    for (int t = 0; t < 4; ++t) acc[t] = (f32x4){0.f, 0.f, 0.f, 0.f};
#pragma unroll
    for (int kt = 0; kt < 16; ++kt) {
        int k0 = kt * 32 + kq * 8;
        bf16x8 a;
        if (k0 < 128) a = *(const bf16x8*)&Xb[(size_t)arow * 128 + k0];
        else          a = *(const bf16x8*)&AGs[lr * LROW + (k0 - 128)];
        const u16* wb = Wf + ((size_t)(kt * 8 + nh * 4)) * 512 + lane * 8;
#pragma unroll
        for (int t = 0; t < 4; ++t) {
            bf16x8 b = *(const bf16x8*)&wb[(size_t)t * 512];
            acc[t] = __builtin_amdgcn_mfma_f32_16x16x32_bf16(a, b, acc[t], 0, 0, 0);
        }
    }
    int ccol = lane & 15;
    int rbase = m0 + rq * 16 + kq * 4;
#pragma unroll
    for (int t = 0; t < 4; ++t) {
        int col = (nh * 4 + t) * 16 + ccol;
        float bv = bias[col];
        float cs = 0.f, cq = 0.f;
#pragma unroll
        for (int r = 0; r < 4; ++r) {
            int rr = rbase + r;
            float val = acc[t][r] + bv;
            if (rr < M) {
                C[(size_t)rr * 128 + col] = f2bf(val);
                cs += val; cq += val * val;
            }
        }
        cs += __shfl_xor(cs, 16); cs += __shfl_xor(cs, 32);
        cq += __shfl_xor(cq, 16); cq += __shfl_xor(cq, 32);
        if (kq == 0) {
            atomicAdd(&sS[col], cs);
            atomicAdd(&sQ[col], cq);
        }
    }
    __syncthreads();
    if (tid < 128) {
        bnpart[(size_t)blockIdx.x * 256 + tid] = sS[tid];
        bnpart[(size_t)blockIdx.x * 256 + 128 + tid] = sQ[tid];
    }
}

// ---------- reduce per-block BN partials -> bnacc[256] (parallel: 256 blocks) ----------
__global__ __launch_bounds__(256) void k_bn_reduce(const float* __restrict__ bnpart,
                                                   float* __restrict__ bnacc, int nb) {
    int c = blockIdx.x;                     // one column per block
    float s = 0.f;
    for (int r = threadIdx.x; r < nb; r += 256)
        s += bnpart[(size_t)r * 256 + c];
    for (int o = 32; o; o >>= 1) s += __shfl_xor(s, o);
    __shared__ float sw[4];
    if ((threadIdx.x & 63) == 0) sw[threadIdx.x >> 6] = s;
    __syncthreads();
    if (threadIdx.x == 0) bnacc[c] = sw[0] + sw[1] + sw[2] + sw[3];
}

// ---------- FUSED layer2: aggregate 64 nodes -> LDS, then MFMA GEMM (N=40) + log_softmax ----------
__global__ __launch_bounds__(512) void k_aggemm2(const u8* __restrict__ H8,
        const int* __restrict__ rowptr, const int* __restrict__ colsrc,
        const float2* __restrict__ elns, const float* __restrict__ er,
        const u16* __restrict__ Hb, const u16* __restrict__ Wf,
        const float* __restrict__ bias, float* __restrict__ out, int M) {
    __shared__ u16 AGs[64 * LROW];
    int tid = threadIdx.x;
    int v = tid >> 6;
    int lane = tid & 63;
    int g = lane >> 4, gl = lane & 15;
    int m0 = blockIdx.x * 64;
#pragma unroll
    for (int it = 0; it < 2; ++it) {
        int lw = v * 8 + it * 4 + g;
        agg_tile(H8, rowptr, colsrc, elns, er, M, m0 + lw, g, gl, &AGs[lw * LROW]);
    }
    __syncthreads();
    if (v >= 4) return;                    // gemm2 is small: waves 0-3 only
    const int NT = 3;
    int lr = v * 16 + (lane & 15);
    int arow = m0 + lr;
    if (arow >= M) arow = M - 1;
    int kq = lane >> 4;
    f32x4 acc[NT];
#pragma unroll
    for (int t = 0; t < NT; ++t) acc[t] = (f32x4){0.f, 0.f, 0.f, 0.f};
#pragma unroll
    for (int kt = 0; kt < 16; ++kt) {
        int k0 = kt * 32 + kq * 8;
        bf16x8 a;
        if (k0 < 128) a = *(const bf16x8*)&Hb[(size_t)arow * 128 + k0];
        else          a = *(const bf16x8*)&AGs[lr * LROW + (k0 - 128)];
        const u16* wb = Wf + ((size_t)kt * NT) * 512 + lane * 8;
#pragma unroll
        for (int t = 0; t < NT; ++t) {
            bf16x8 b = *(const bf16x8*)&wb[(size_t)t * 512];
            acc[t] = __builtin_amdgcn_mfma_f32_16x16x32_bf16(a, b, acc[t], 0, 0, 0);
        }
    }
    int ccol = lane & 15;
    int rbase = m0 + v * 16 + kq * 4;
    bool valid[NT];
    float bv[NT];
#pragma unroll
    for (int t = 0; t < NT; ++t) {
        int col = t * 16 + ccol;
        valid[t] = (col < 40);
        bv[t] = valid[t] ? bias[col] : 0.f;
    }
#pragma unroll
    for (int r = 0; r < 4; ++r) {
        float vv[NT];
#pragma unroll
        for (int t = 0; t < NT; ++t) vv[t] = valid[t] ? (acc[t][r] + bv[t]) : -INFINITY;
        float mx = fmaxf(fmaxf(vv[0], vv[1]), vv[2]);
        for (int o = 1; o < 16; o <<= 1) mx = fmaxf(mx, __shfl_xor(mx, o));
        float se = 0.f;
#pragma unroll
        for (int t = 0; t < NT; ++t) se += valid[t] ? __expf(vv[t] - mx) : 0.f;
        for (int o = 1; o < 16; o <<= 1) se += __shfl_xor(se, o);
        float lse = mx + logf(se);
        int rr = rbase + r;
        if (rr < M) {
#pragma unroll
            for (int t = 0; t < NT; ++t) {
                int col = t * 16 + ccol;
                if (valid[t]) out[(size_t)rr * 40 + col] = vv[t] - lse;
            }
        }
    }
}

// ---------- fused: BN-final + BN+ReLU -> bf16 h + fp8 h8 + layer-2 logits ----------
__global__ __launch_bounds__(256) void k_bnorm_dots(const u16* __restrict__ Hp,
        const float* __restrict__ bnacc, const float* __restrict__ g, const float* __restrict__ be,
        const float* __restrict__ vl, const float* __restrict__ vr,
        const float* __restrict__ ns,
        u16* __restrict__ H, u8* __restrict__ H8,
        float2* __restrict__ elns, float* __restrict__ er, float Nf, int n) {
    int w = (blockIdx.x * blockDim.x + threadIdx.x) >> 6;
    int lane = threadIdx.x & 63;
    if (w >= n) return;
    int c0 = lane * 2, c1 = lane * 2 + 1;
    float mu0 = bnacc[c0] / Nf, mu1 = bnacc[c1] / Nf;
    float var0 = bnacc[128 + c0] / Nf - mu0 * mu0;
    float var1 = bnacc[128 + c1] / Nf - mu1 * mu1;
    float sc0 = g[c0] * rsqrtf(var0 + 1e-5f);
    float sc1 = g[c1] * rsqrtf(var1 + 1e-5f);
    float sh0 = be[c0] - mu0 * sc0;
    float sh1 = be[c1] - mu1 * sc1;
    u32 hu = *(const u32*)&Hp[(size_t)w * 128 + lane * 2];
    float vx = bf2f((u16)hu), vy = bf2f((u16)(hu >> 16));
    float h0 = fmaxf(vx * sc0 + sh0, 0.f);
    float h1 = fmaxf(vy * sc1 + sh1, 0.f);
    *(u32*)&H[(size_t)w * 128 + lane * 2] = cvtpk_bf16(h0, h1);
    u16 q = (u16)f2fp8(h0) | ((u16)f2fp8(h1) << 8);
    *(u16*)&H8[(size_t)w * 128 + lane * 2] = q;
    float2 a = *(const float2*)&vl[lane * 2];
    float2 b = *(const float2*)&vr[lane * 2];
    float dl = h0 * a.x + h1 * a.y;
    float dr = h0 * b.x + h1 * b.y;
    for (int off = 32; off; off >>= 1) {
        dl += __shfl_down(dl, off);
        dr += __shfl_down(dr, off);
    }
    if (lane == 0) { elns[w] = make_float2(dl, ns[w]); er[w] = dr; }
}

extern "C" void kernel_launch(void* const* d_in, const int* in_sizes, int n_in,
                              void* d_out, int out_size, void* d_ws, size_t ws_size,
                              hipStream_t stream) {
    const float* x    = (const float*)d_in[0];
    const int*   src  = (const int*)d_in[1];
    const int*   dst  = (const int*)d_in[2];
    const float* w11s = (const float*)d_in[3];
    const float* w11n = (const float*)d_in[4];
    const float* b11  = (const float*)d_in[5];
    const float* w12  = (const float*)d_in[6];
    const float* b12  = (const float*)d_in[7];
    const float* w13  = (const float*)d_in[8];
    const float* a13l = (const float*)d_in[9];
    const float* a13r = (const float*)d_in[10];
    const float* b13  = (const float*)d_in[11];
    const float* cw1  = (const float*)d_in[12];
    const float* g    = (const float*)d_in[13];
    const float* be   = (const float*)d_in[14];
    const float* w21s = (const float*)d_in[15];
    const float* w21n = (const float*)d_in[16];
    const float* b21  = (const float*)d_in[17];
    const float* w22  = (const float*)d_in[18];
    const float* b22  = (const float*)d_in[19];
    const float* w23  = (const float*)d_in[20];
    const float* a23l = (const float*)d_in[21];
    const float* a23r = (const float*)d_in[22];
    const float* b23  = (const float*)d_in[23];
    const float* cw2  = (const float*)d_in[24];

    const int N = in_sizes[0] / DIN;
    const int E = in_sizes[1];

    char* ws = (char*)d_ws;
    size_t off = 0;
    auto alloc = [&](size_t bytes) { size_t o = off; off += (bytes + 255) & ~(size_t)255; return o; };
    u16*   Xb     = (u16*)(ws + alloc((size_t)N * 128 * 2));
    u8*    Xq     = (u8*)(ws + alloc((size_t)(N + 1) * 128));     // +1 zero row
    u16*   scrA   = (u16*)(ws + alloc((size_t)N * 384 * 2));      // overlay region (partialsS)
    u16*   hpre   = (u16*)(ws + alloc((size_t)N * 128 * 2));
    u16*   h      = (u16*)(ws + alloc((size_t)N * 128 * 2));
    u8*    h8     = (u8*)(ws + alloc((size_t)(N + 1) * 128));     // +1 zero row
    int*   col    = (int*)(ws + alloc((size_t)E * 4));
    u8*    wsrank = (u8*)(ws + alloc((size_t)E));
    int*   rowptr = (int*)(ws + alloc((size_t)(N + 1) * 4));
    int*   excl   = (int*)(ws + alloc((size_t)NPAD * 4));
    int*   bsum   = (int*)(ws + alloc(256 * 4));
    float* ns     = (float*)(ws + alloc((size_t)N * 4));
    float2* elns  = (float2*)(ws + alloc((size_t)N * 8));
    float* er     = (float*)(ws + alloc((size_t)N * 4));
    u16*   Wf1    = (u16*)(ws + alloc((size_t)16 * 8 * 64 * 8 * 2));
    u16*   Wf2    = (u16*)(ws + alloc((size_t)16 * 3 * 64 * 8 * 2));
    float* bc1    = (float*)(ws + alloc(128 * 4));
    float* bc2    = (float*)(ws + alloc(40 * 4));
    float* vattn  = (float*)(ws + alloc(512 * 4));
    float* bnacc  = (float*)(ws + alloc(256 * 4));
    float* bnpart = (float*)(ws + alloc((size_t)((N + 63) / 64) * 256 * 4));

    // Overlays: partials (u8, 12.85 MB each) live only hist2->place2.
    u8* partialsS = (u8*)scrA;
    u8* partialsD = (u8*)hpre;

    int eps = (E + NSTRIPE - 1) / NSTRIPE;
    int wb = (N * 64 + 255) / 256;
    int gb = (N + 63) / 64;
    int pb = NPAD / 256;

    // fused weight prep (Wf1 + Wf2 + attn + biases + zero rows)
    k_prep<<<(90856 + 255) / 256, 256, 0, stream>>>(
        w11s, w11n, w12, w13, b11, b12, b13, cw1,
        w21s, w21n, w22, w23, b21, b22, b23, cw2,
        a13l, a13r, a23l, a23r, Wf1, Wf2, bc1, bc2, vattn,
        (u32*)(Xq + (size_t)N * 128), (u32*)(h8 + (size_t)N * 128));

    // CSR build: single-chunk u8 histogram (1 edge pass), prefix+scan
    k_hist2<<<NSTRIPE, 1024, 0, stream>>>(src, dst, partialsS, partialsD, wsrank, E, eps);
    k_pfx2<<<pb, 256, 0, stream>>>(partialsS, partialsD, excl, bsum, ns, N);

    // cvt/dots + rowptr finalize (absorbs scan2+scan3), then placement
    k_cvt_dots<<<wb, 256, 0, stream>>>(x, vattn, vattn + 128, ns, excl, bsum,
                                       Xb, Xq, elns, er, rowptr, N, E, pb);
    {
        dim3 pg(NSTRIPE, 4);
        k_place2<<<pg, 256, 0, stream>>>(src, dst, rowptr, partialsD, wsrank, col, E, eps);
    }

    // ---- layer 1 (fused agg+gemm; AG stays in LDS) ----
    k_aggemm1<<<gb, 512, 0, stream>>>(Xq, rowptr, col, elns, er,
                                      Xb, Wf1, bc1, hpre, bnpart, N);

    // BN partial reduce (parallel), then fused final+norm+logits
    k_bn_reduce<<<256, 256, 0, stream>>>(bnpart, bnacc, gb);
    k_bnorm_dots<<<wb, 256, 0, stream>>>(hpre, bnacc, g, be, vattn + 256, vattn + 384, ns,
                                         h, h8, elns, er, (float)N, N);

    // ---- layer 2 (fused agg+gemm+log_softmax) ----
    k_aggemm2<<<gb, 512, 0, stream>>>(h8, rowptr, col, elns, er,
                                      h, Wf2, bc2, (float*)d_out, N);
}

// Round 12
// 375.242 us; speedup vs baseline: 1.0827x; 1.0827x over previous
//
#include <hip/hip_runtime.h>
#include <hip/hip_bf16.h>
#include <math.h>

#define DIN 128
#define DH  128
#define DC  40

#define NSTRIPE 256
#define NPAD    50176          // padded node slots (196 * 256)
#define H8_WORDS (NPAD / 4)    // u8-packed histogram words = 12544

typedef unsigned short u16;
typedef unsigned int u32;
typedef unsigned char u8;
typedef __attribute__((ext_vector_type(2))) float f32x2;
typedef __attribute__((ext_vector_type(4))) float f32x4;
typedef __attribute__((ext_vector_type(8))) short bf16x8;

static __device__ __forceinline__ float bf2f(u16 u) {
    union { u32 i; float f; } v; v.i = ((u32)u) << 16; return v.f;
}
static __device__ __forceinline__ u16 f2bf(float f) {
    __hip_bfloat16 h = __float2bfloat16(f);
    union { __hip_bfloat16 h; u16 u; } v; v.h = h; return v.u;
}
static __device__ __forceinline__ u32 pack2bf(float a, float b) {
    return ((u32)f2bf(b) << 16) | (u32)f2bf(a);
}
// 1-inst packed f32->bf16 pair (lo = a, hi = b); RNE, matches __float2bfloat16
static __device__ __forceinline__ u32 cvtpk_bf16(float a, float b) {
    u32 r;
    asm("v_cvt_pk_bf16_f32 %0, %1, %2" : "=v"(r) : "v"(a), "v"(b));
    return r;
}

// ---------- fp8 e4m3fn helpers ----------
static __device__ __forceinline__ u8 f2fp8(float f) {
    u32 s = (__float_as_uint(f) >> 31) << 7;
    float a = fabsf(f);
    a = fminf(a, 448.f);
    if (a < 0.015625f) {
        int q = (int)rintf(a * 512.f);
        return (u8)(s | (u32)q);
    }
    u32 x = __float_as_uint(a);
    u32 lsb = (x >> 20) & 1;
    x += 0x0007FFFF + lsb;
    u32 e = (x >> 23) - 120;
    u32 m = (x >> 20) & 7;
    return (u8)(s | (e << 3) | m);
}

#if __has_builtin(__builtin_amdgcn_cvt_pk_f32_fp8)
template<bool HI>
static __device__ __forceinline__ f32x2 fp8pk(u32 w) {
    return __builtin_amdgcn_cvt_pk_f32_fp8((int)w, HI);
}
#else
static __device__ __forceinline__ float fp8dec1(u32 byte) {
    u32 s = (byte >> 7) & 1, em = byte & 0x7F;
    float v = __uint_as_float((s << 31) | (em << 20)) * 0x1p120f;
    return v;
}
template<bool HI>
static __device__ __forceinline__ f32x2 fp8pk(u32 w) {
    u32 b0 = HI ? ((w >> 16) & 0xff) : (w & 0xff);
    u32 b1 = HI ? ((w >> 24) & 0xff) : ((w >> 8) & 0xff);
    f32x2 r; r.x = fp8dec1(b0); r.y = fp8dec1(b1); return r;
}
#endif

// ---------- fused weight prep: w1 frags + w2 frags + attn dots + biases
// ---------- + zero rows of Xq/h8 (for guard-free k_agg) ----------
__global__ __launch_bounds__(256) void k_prep(
        const float* w11s, const float* w11n, const float* w12, const float* w13,
        const float* b11, const float* b12, const float* b13, const float* cw1,
        const float* w21s, const float* w21n, const float* w22, const float* w23,
        const float* b21, const float* b22, const float* b23, const float* cw2,
        const float* a13l, const float* a13r, const float* a23l, const float* a23r,
        u16* __restrict__ Wf1, u16* __restrict__ Wf2,
        float* __restrict__ bc1, float* __restrict__ bc2, float* __restrict__ vattn,
        u32* __restrict__ zq, u32* __restrict__ zh) {
    int i = blockIdx.x * 256 + threadIdx.x;
    float s1 = cw1[0] + cw1[1] + cw1[2];
    float u0 = cw1[0] / s1, u1 = cw1[1] / s1, u2 = cw1[2] / s1;
    float s2 = cw2[0] + cw2[1] + cw2[2];
    float q0 = cw2[0] / s2, q1 = cw2[1] / s2, q2 = cw2[2] / s2;
    if (i < 65536) {                                   // Wf1 frags
        int j = i & 7, lane = (i >> 3) & 63, nt = (i >> 9) & 7, kt = i >> 12;
        int k = kt * 32 + ((lane >> 4) << 3) + j;
        int n = nt * 16 + (lane & 15);
        float v;
        if (k < 128)      v = u0 * w11s[k * 128 + n];
        else if (k < 256) v = u0 * w11n[(k - 128) * 128 + n];
        else if (k < 384) v = u1 * w12[(k - 256) * 128 + n];
        else              v = u2 * w13[(k - 384) * 128 + n];
        Wf1[i] = f2bf(v);
    } else if (i < 90112) {                            // Wf2 frags
        int i2 = i - 65536;
        int j = i2 & 7;
        int l2 = i2 >> 3;
        int lane = l2 & 63;
        int t2 = l2 >> 6;
        int nt = t2 % 3, kt = t2 / 3;
        int k = kt * 32 + ((lane >> 4) << 3) + j;
        int n = nt * 16 + (lane & 15);
        float v = 0.f;
        if (n < 40) {
            if (k < 128)      v = q0 * w21s[k * 40 + n];
            else if (k < 256) v = q0 * w21n[(k - 128) * 40 + n];
            else if (k < 384) v = q1 * w22[(k - 256) * 40 + n];
            else              v = q2 * w23[(k - 384) * 40 + n];
        }
        Wf2[i2] = f2bf(v);
    } else if (i < 90624) {                            // attn dots
        int t = i - 90112;
        if (t < 128) {
            float s = 0; for (int j = 0; j < 128; ++j) s += w13[t * 128 + j] * a13l[j];
            vattn[t] = s;
        } else if (t < 256) {
            int r = t - 128; float s = 0; for (int j = 0; j < 128; ++j) s += w13[r * 128 + j] * a13r[j];
            vattn[t] = s;
        } else if (t < 384) {
            int r = t - 256; float s = 0; for (int j = 0; j < 40; ++j) s += w23[r * 40 + j] * a23l[j];
            vattn[t] = s;
        } else {
            int r = t - 384; float s = 0; for (int j = 0; j < 40; ++j) s += w23[r * 40 + j] * a23r[j];
            vattn[t] = s;
        }
    } else if (i < 90752) {                            // bc1
        int c = i - 90624;
        bc1[c] = u0 * b11[c] + u1 * b12[c] + u2 * b13[c];
    } else if (i < 90792) {                            // bc2
        int c = i - 90752;
        bc2[c] = q0 * b21[c] + q1 * b22[c] + q2 * b23[c];
    } else if (i < 90856) {                            // zero rows Xq[n], h8[n]
        int t = i - 90792;
        if (t < 32) zq[t] = 0u; else zh[t - 32] = 0u;
    }
}

// ---------- CSR build: single-chunk dual LDS histogram, ONE edge pass ----------
__global__ __launch_bounds__(512) void k_hist2(const int* __restrict__ src,
        const int* __restrict__ dst,
        u8* __restrict__ partialsS, u8* __restrict__ partialsD,
        u8* __restrict__ wsrank, int E, int eps) {
    __shared__ u32 histD[H8_WORDS];
    __shared__ u32 histS[H8_WORDS];
    int stripe = blockIdx.x;
    for (int i = threadIdx.x; i < H8_WORDS; i += 512) { histD[i] = 0; histS[i] = 0; }
    __syncthreads();
    int e0 = stripe * eps;
    int e1 = e0 + eps; if (e1 > E) e1 = E;
    for (int e = e0 + threadIdx.x; e < e1; e += 512) {
        int ks = src[e];
        int kd = dst[e];
        atomicAdd(&histS[ks >> 2], 1u << ((ks & 3) * 8));
        u32 old = atomicAdd(&histD[kd >> 2], 1u << ((kd & 3) * 8));
        wsrank[e] = (u8)((old >> ((kd & 3) * 8)) & 0xff);
    }
    __syncthreads();
    u32* prowS = (u32*)(partialsS + (size_t)stripe * NPAD);
    u32* prowD = (u32*)(partialsD + (size_t)stripe * NPAD);
    for (int i = threadIdx.x; i < H8_WORDS; i += 512) { prowD[i] = histD[i]; prowS[i] = histS[i]; }
}

// per-node: src totals -> ns; dst prefix in place (u8) -> indeg.
// Then in-block counting sort by degree -> perm, and the block-scan runs in
// RANK order so the CSR (rowptrR/col) is laid out degree-sorted: k_agg gets
// contiguous colsrc AND degree-matched waves.
__global__ __launch_bounds__(256) void k_pfx2(const u8* __restrict__ partialsS,
        u8* __restrict__ partialsD,
        int* __restrict__ excl, int* __restrict__ bsum,
        float* __restrict__ ns, int* __restrict__ perm, int n) {
    int node = blockIdx.x * 256 + threadIdx.x;
    int runS = 0;
    for (int s0 = 0; s0 < NSTRIPE; s0 += 16) {
        u8 c[16];
#pragma unroll
        for (int i = 0; i < 16; ++i) c[i] = partialsS[(size_t)(s0 + i) * NPAD + node];
#pragma unroll
        for (int i = 0; i < 16; ++i) runS += c[i];
    }
    int runD = 0;
    for (int s0 = 0; s0 < NSTRIPE; s0 += 16) {
        u8 c[16];
#pragma unroll
        for (int i = 0; i < 16; ++i) c[i] = partialsD[(size_t)(s0 + i) * NPAD + node];
#pragma unroll
        for (int i = 0; i < 16; ++i) {
            partialsD[(size_t)(s0 + i) * NPAD + node] = (u8)runD;
            runD += c[i];
        }
    }
    if (node < n) {
        int d = runS < 1 ? 1 : runS;
        ns[node] = rsqrtf((float)d);
    }
    __shared__ int sh[256];
    __shared__ int bhist[256];
    __shared__ int bcur[256];
    // counting sort by (clamped) degree -> rank within block
    int d8 = runD > 255 ? 255 : runD;
    bhist[threadIdx.x] = 0;
    __syncthreads();
    atomicAdd(&bhist[d8], 1);
    __syncthreads();
    int bval = bhist[threadIdx.x];
    sh[threadIdx.x] = bval; __syncthreads();
    for (int o = 1; o < 256; o <<= 1) {
        int t = (threadIdx.x >= o) ? sh[threadIdx.x - o] : 0;
        __syncthreads(); sh[threadIdx.x] += t; __syncthreads();
    }
    bcur[threadIdx.x] = sh[threadIdx.x] - bval;   // exclusive bin start
    __syncthreads();
    int rank = atomicAdd(&bcur[d8], 1);
    perm[blockIdx.x * 256 + rank] = node;
    __syncthreads();
    // degree by RANK, then block-scan in rank order -> excl (rank-indexed)
    sh[rank] = runD;
    __syncthreads();
    int dval = sh[threadIdx.x];
    for (int o = 1; o < 256; o <<= 1) {
        int t = (threadIdx.x >= o) ? sh[threadIdx.x - o] : 0;
        __syncthreads(); sh[threadIdx.x] += t; __syncthreads();
    }
    excl[blockIdx.x * 256 + threadIdx.x] = sh[threadIdx.x] - dval;
    if (threadIdx.x == 255) bsum[blockIdx.x] = sh[255];
}

// atomic-free placement: per-NODE row start (rowptrN) + stripe-prefix + rank
__global__ __launch_bounds__(256) void k_place2(const int* __restrict__ src,
        const int* __restrict__ dst, const int* __restrict__ rowptrN,
        const u8* __restrict__ partials, const u8* __restrict__ wsrank,
        int* __restrict__ col, int E, int eps) {
    int stripe = blockIdx.x;
    const u8* prow = partials + (size_t)stripe * NPAD;
    int sub = (eps + 3) >> 2;
    int e0 = stripe * eps + blockIdx.y * sub;
    int e1 = e0 + sub;
    int cap = stripe * eps + eps; if (cap > E) cap = E;
    if (e1 > cap) e1 = cap;
    for (int e = e0 + threadIdx.x; e < e1; e += 256) {
        int d = dst[e];
        col[rowptrN[d] + prow[d] + wsrank[e]] = src[e];
    }
}

// ---------- fused: f32 x -> bf16 Xb + fp8 Xq + logits + rank-ordered rowptr ----------
// rowptrR[r] (rank-indexed, NPAD+1) for k_agg; rowptrN[node] scatter for place2.
__global__ __launch_bounds__(256) void k_cvt_dots(const float* __restrict__ X,
        const float* __restrict__ vl, const float* __restrict__ vr, const float* __restrict__ ns,
        const int* __restrict__ excl, const int* __restrict__ bsum,
        const int* __restrict__ perm,
        u16* __restrict__ Xb, u8* __restrict__ Xq,
        float2* __restrict__ elns, float* __restrict__ er,
        int* __restrict__ rowptrR, int* __restrict__ rowptrN,
        int n, int E, int pb, int npad) {
    __shared__ int sh[256], shE[256];
    int t = threadIdx.x;
    int v = (t < pb) ? bsum[t] : 0;
    sh[t] = v; __syncthreads();
    for (int o = 1; o < 256; o <<= 1) {
        int u = (t >= o) ? sh[t - o] : 0;
        __syncthreads(); sh[t] += u; __syncthreads();
    }
    shE[t] = sh[t] - v;        // exclusive scan of block sums
    __syncthreads();
    if (blockIdx.x == 0) {     // tail ranks n..npad-1 + sentinel
        for (int r = n + t; r <= npad; r += 256) {
            if (r < npad) {
                int val = excl[r] + shE[r >> 8];
                rowptrR[r] = val;
                int pn = perm[r];
                if (pn < n) rowptrN[pn] = val;
            } else {
                rowptrR[npad] = E;
            }
        }
    }
    int w = (blockIdx.x * blockDim.x + t) >> 6;
    int lane = t & 63;
    if (w >= n) return;
    float2 xv = *(const float2*)&X[(size_t)w * 128 + lane * 2];
    *(u32*)&Xb[(size_t)w * 128 + lane * 2] = cvtpk_bf16(xv.x, xv.y);
    u16 q = (u16)f2fp8(xv.x) | ((u16)f2fp8(xv.y) << 8);
    *(u16*)&Xq[(size_t)w * 128 + lane * 2] = q;
    float2 a = *(const float2*)&vl[lane * 2];
    float2 b = *(const float2*)&vr[lane * 2];
    float dl = xv.x * a.x + xv.y * a.y;
    float dr = xv.x * b.x + xv.y * b.y;
    for (int off = 32; off; off >>= 1) {
        dl += __shfl_down(dl, off);
        dr += __shfl_down(dr, off);
    }
    if (lane == 0) {
        int val = excl[w] + shE[w >> 8];     // w doubles as rank index here
        rowptrR[w] = val;
        int pn = perm[w];
        if (pn < n) rowptrN[pn] = val;
        elns[w] = make_float2(dl, ns[w]);    // node-indexed
        er[w] = dr;
    }
}

// ---------- aggregation: 4 ranks/wave, one 16-lane group per rank ----------
// CSR is degree-sorted by rank: contiguous colsrc reads, degree-matched waves.
// Output node w = perm[r]; AG/er scattered only within a 256-node window (L2).
__global__ __launch_bounds__(256) void k_agg(const u8* __restrict__ Xq,
        const int* __restrict__ rowptrR, const int* __restrict__ colsrc,
        const float2* __restrict__ elns, const float* __restrict__ er,
        const int* __restrict__ perm,
        u16* __restrict__ AG, int n, int npad) {
    int wave = (blockIdx.x * blockDim.x + threadIdx.x) >> 6;
    int lane = threadIdx.x & 63;
    int g = lane >> 4, gl = lane & 15;
    int r = wave * 4 + g;
    int w = (r < npad) ? perm[r] : n;
    bool act = (w < n);
    int beg = 0, k = 0;
    if (r < npad) { beg = rowptrR[r]; k = rowptrR[r + 1] - beg; }
    float erd = act ? er[w] : 0.f;
    int kmax = k;
    kmax = max(kmax, __shfl_xor(kmax, 16));
    kmax = max(kmax, __shfl_xor(kmax, 32));
    f32x2 aS2[4] = {}, aG2[4] = {}, aA2[4] = {};
    float ssum_l = 0.f;
    for (int c = 0; c < kmax; c += 16) {
        int cnt = k - c; cnt = cnt < 0 ? 0 : (cnt > 16 ? 16 : cnt);
        int s = n; float p = 0.f, nsl = 0.f;
        if (gl < cnt) {
            s = colsrc[beg + c + gl];
            float2 v = elns[s];
            float t = v.x + erd;
            t = t > 0.f ? t : 0.2f * t;            // leaky_relu 0.2
            p = __expf(t);
            nsl = v.y;
        }
        ssum_l += p;
        int cm = kmax - c; if (cm > 16) cm = 16;   // wave-uniform step bound
#pragma unroll 8
        for (int t = 0; t < cm; ++t) {
            int j = (g << 4) + t;                  // edge t of MY group
            int sj = __shfl(s, j);
            float pj = __shfl(p, j);
            float nsj = __shfl(nsl, j);
            uint2 xq = *(const uint2*)&Xq[(size_t)sj * 128 + gl * 8];
            f32x2 xv2[4] = {fp8pk<false>(xq.x), fp8pk<true>(xq.x),
                            fp8pk<false>(xq.y), fp8pk<true>(xq.y)};
            f32x2 ns2 = {nsj, nsj}, pw = {pj, pj};
#pragma unroll
            for (int q = 0; q < 4; ++q) {
                aS2[q] += xv2[q];
                aG2[q] += ns2 * xv2[q];
                aA2[q] += pw * xv2[q];
            }
        }
    }
    // softmax denom: reduce within the 16-lane group
    ssum_l += __shfl_xor(ssum_l, 1);
    ssum_l += __shfl_xor(ssum_l, 2);
    ssum_l += __shfl_xor(ssum_l, 4);
    ssum_l += __shfl_xor(ssum_l, 8);
    if (!act) return;
    int kc = k < 1 ? 1 : k;
    float invk = 1.f / (float)kc;
    float ndd = rsqrtf((float)kc);
    float gi = 1.f / fmaxf(ssum_l, 1e-9f);
    u16* row = AG + (size_t)w * 384;
    *(uint4*)&row[gl * 8] = make_uint4(
        pack2bf(aS2[0][0] * invk, aS2[0][1] * invk), pack2bf(aS2[1][0] * invk, aS2[1][1] * invk),
        pack2bf(aS2[2][0] * invk, aS2[2][1] * invk), pack2bf(aS2[3][0] * invk, aS2[3][1] * invk));
    *(uint4*)&row[128 + gl * 8] = make_uint4(
        pack2bf(aG2[0][0] * ndd, aG2[0][1] * ndd), pack2bf(aG2[1][0] * ndd, aG2[1][1] * ndd),
        pack2bf(aG2[2][0] * ndd, aG2[2][1] * ndd), pack2bf(aG2[3][0] * ndd, aG2[3][1] * ndd));
    *(uint4*)&row[256 + gl * 8] = make_uint4(
        pack2bf(aA2[0][0] * gi, aA2[0][1] * gi), pack2bf(aA2[1][0] * gi, aA2[1][1] * gi),
        pack2bf(aA2[2][0] * gi, aA2[2][1] * gi), pack2bf(aA2[3][0] * gi, aA2[3][1] * gi));
}

// ---------- MFMA GEMM layer1 + per-block BN column partials (no atomics) ----------
__global__ __launch_bounds__(256) void k_gemm1(const u16* __restrict__ Xb,
        const u16* __restrict__ AG, const u16* __restrict__ Wf,
        const float* __restrict__ bias, u16* __restrict__ C,
        float* __restrict__ bnpart, int M) {
    const int NT = 8;
    int wave = threadIdx.x >> 6;
    int lane = threadIdx.x & 63;
    int m0 = blockIdx.x * 64 + wave * 16;
    int arow = m0 + (lane & 15);
    if (arow >= M) arow = M - 1;
    int kq = lane >> 4;
    f32x4 acc[NT];
#pragma unroll
    for (int t = 0; t < NT; ++t) acc[t] = (f32x4){0.f, 0.f, 0.f, 0.f};
#pragma unroll
    for (int kt = 0; kt < 16; ++kt) {
        int k0 = kt * 32 + kq * 8;
        bf16x8 a;
        if (k0 < 128) a = *(const bf16x8*)&Xb[(size_t)arow * 128 + k0];
        else          a = *(const bf16x8*)&AG[(size_t)arow * 384 + (k0 - 128)];
        const u16* wb = Wf + ((size_t)kt * NT) * 512 + lane * 8;
#pragma unroll
        for (int t = 0; t < NT; ++t) {
            bf16x8 b = *(const bf16x8*)&wb[(size_t)t * 512];
            acc[t] = __builtin_amdgcn_mfma_f32_16x16x32_bf16(a, b, acc[t], 0, 0, 0);
        }
    }
    __shared__ float sS[128], sQ[128];
    if (threadIdx.x < 128) { sS[threadIdx.x] = 0.f; sQ[threadIdx.x] = 0.f; }
    __syncthreads();
    int ccol = lane & 15;
    int rbase = m0 + kq * 4;
#pragma unroll
    for (int t = 0; t < NT; ++t) {
        int col = t * 16 + ccol;
        float bv = bias[col];
        float cs = 0.f, cq = 0.f;
#pragma unroll
        for (int r = 0; r < 4; ++r) {
            int rr = rbase + r;
            float v = acc[t][r] + bv;
            if (rr < M) {
                C[(size_t)rr * 128 + col] = f2bf(v);
                cs += v; cq += v * v;
            }
        }
        cs += __shfl_xor(cs, 16); cs += __shfl_xor(cs, 32);
        cq += __shfl_xor(cq, 16); cq += __shfl_xor(cq, 32);
        if (kq == 0) {
            atomicAdd(&sS[col], cs);
            atomicAdd(&sQ[col], cq);
        }
    }
    __syncthreads();
    if (threadIdx.x < 128) {
        bnpart[(size_t)blockIdx.x * 256 + threadIdx.x] = sS[threadIdx.x];
        bnpart[(size_t)blockIdx.x * 256 + 128 + threadIdx.x] = sQ[threadIdx.x];
    }
}

// ---------- reduce per-block BN partials -> bnacc[256] (parallel: 256 blocks) ----------
__global__ __launch_bounds__(256) void k_bn_reduce(const float* __restrict__ bnpart,
                                                   float* __restrict__ bnacc, int nb) {
    int c = blockIdx.x;                     // one column per block
    float s = 0.f;
    for (int r = threadIdx.x; r < nb; r += 256)
        s += bnpart[(size_t)r * 256 + c];
    for (int o = 32; o; o >>= 1) s += __shfl_xor(s, o);
    __shared__ float sw[4];
    if ((threadIdx.x & 63) == 0) sw[threadIdx.x >> 6] = s;
    __syncthreads();
    if (threadIdx.x == 0) bnacc[c] = sw[0] + sw[1] + sw[2] + sw[3];
}

// ---------- MFMA GEMM layer2 (N=40) fused with log_softmax, writes f32 out ----------
__global__ __launch_bounds__(256) void k_gemm2_lsm(const u16* __restrict__ Xb,
        const u16* __restrict__ AG, const u16* __restrict__ Wf,
        const float* __restrict__ bias, float* __restrict__ out, int M) {
    const int NT = 3;
    int wave = threadIdx.x >> 6;
    int lane = threadIdx.x & 63;
    int m0 = blockIdx.x * 64 + wave * 16;
    int arow = m0 + (lane & 15);
    if (arow >= M) arow = M - 1;
    int kq = lane >> 4;
    f32x4 acc[NT];
#pragma unroll
    for (int t = 0; t < NT; ++t) acc[t] = (f32x4){0.f, 0.f, 0.f, 0.f};
#pragma unroll
    for (int kt = 0; kt < 16; ++kt) {
        int k0 = kt * 32 + kq * 8;
        bf16x8 a;
        if (k0 < 128) a = *(const bf16x8*)&Xb[(size_t)arow * 128 + k0];
        else          a = *(const bf16x8*)&AG[(size_t)arow * 384 + (k0 - 128)];
        const u16* wb = Wf + ((size_t)kt * NT) * 512 + lane * 8;
#pragma unroll
        for (int t = 0; t < NT; ++t) {
            bf16x8 b = *(const bf16x8*)&wb[(size_t)t * 512];
            acc[t] = __builtin_amdgcn_mfma_f32_16x16x32_bf16(a, b, acc[t], 0, 0, 0);
        }
    }
    int ccol = lane & 15;
    int rbase = m0 + kq * 4;
    bool valid[NT];
    float bv[NT];
#pragma unroll
    for (int t = 0; t < NT; ++t) {
        int col = t * 16 + ccol;
        valid[t] = (col < 40);
        bv[t] = valid[t] ? bias[col] : 0.f;
    }
#pragma unroll
    for (int r = 0; r < 4; ++r) {
        float v[NT];
#pragma unroll
        for (int t = 0; t < NT; ++t) v[t] = valid[t] ? (acc[t][r] + bv[t]) : -INFINITY;
        float mx = fmaxf(fmaxf(v[0], v[1]), v[2]);
        for (int o = 1; o < 16; o <<= 1) mx = fmaxf(mx, __shfl_xor(mx, o));
        float se = 0.f;
#pragma unroll
        for (int t = 0; t < NT; ++t) se += valid[t] ? __expf(v[t] - mx) : 0.f;
        for (int o = 1; o < 16; o <<= 1) se += __shfl_xor(se, o);
        float lse = mx + logf(se);
        int rr = rbase + r;
        if (rr < M) {
#pragma unroll
            for (int t = 0; t < NT; ++t) {
                int col = t * 16 + ccol;
                if (valid[t]) out[(size_t)rr * 40 + col] = v[t] - lse;
            }
        }
    }
}

// ---------- fused: BN-final + BN+ReLU -> bf16 h + fp8 h8 + layer-2 logits ----------
__global__ __launch_bounds__(256) void k_bnorm_dots(const u16* __restrict__ Hp,
        const float* __restrict__ bnacc, const float* __restrict__ g, const float* __restrict__ be,
        const float* __restrict__ vl, const float* __restrict__ vr,
        const float* __restrict__ ns,
        u16* __restrict__ H, u8* __restrict__ H8,
        float2* __restrict__ elns, float* __restrict__ er, float Nf, int n) {
    int w = (blockIdx.x * blockDim.x + threadIdx.x) >> 6;
    int lane = threadIdx.x & 63;
    if (w >= n) return;
    int c0 = lane * 2, c1 = lane * 2 + 1;
    float mu0 = bnacc[c0] / Nf, mu1 = bnacc[c1] / Nf;
    float var0 = bnacc[128 + c0] / Nf - mu0 * mu0;
    float var1 = bnacc[128 + c1] / Nf - mu1 * mu1;
    float sc0 = g[c0] * rsqrtf(var0 + 1e-5f);
    float sc1 = g[c1] * rsqrtf(var1 + 1e-5f);
    float sh0 = be[c0] - mu0 * sc0;
    float sh1 = be[c1] - mu1 * sc1;
    u32 hu = *(const u32*)&Hp[(size_t)w * 128 + lane * 2];
    float vx = bf2f((u16)hu), vy = bf2f((u16)(hu >> 16));
    float h0 = fmaxf(vx * sc0 + sh0, 0.f);
    float h1 = fmaxf(vy * sc1 + sh1, 0.f);
    *(u32*)&H[(size_t)w * 128 + lane * 2] = cvtpk_bf16(h0, h1);
    u16 q = (u16)f2fp8(h0) | ((u16)f2fp8(h1) << 8);
    *(u16*)&H8[(size_t)w * 128 + lane * 2] = q;
    float2 a = *(const float2*)&vl[lane * 2];
    float2 b = *(const float2*)&vr[lane * 2];
    float dl = h0 * a.x + h1 * a.y;
    float dr = h0 * b.x + h1 * b.y;
    for (int off = 32; off; off >>= 1) {
        dl += __shfl_down(dl, off);
        dr += __shfl_down(dr, off);
    }
    if (lane == 0) { elns[w] = make_float2(dl, ns[w]); er[w] = dr; }
}

extern "C" void kernel_launch(void* const* d_in, const int* in_sizes, int n_in,
                              void* d_out, int out_size, void* d_ws, size_t ws_size,
                              hipStream_t stream) {
    const float* x    = (const float*)d_in[0];
    const int*   src  = (const int*)d_in[1];
    const int*   dst  = (const int*)d_in[2];
    const float* w11s = (const float*)d_in[3];
    const float* w11n = (const float*)d_in[4];
    const float* b11  = (const float*)d_in[5];
    const float* w12  = (const float*)d_in[6];
    const float* b12  = (const float*)d_in[7];
    const float* w13  = (const float*)d_in[8];
    const float* a13l = (const float*)d_in[9];
    const float* a13r = (const float*)d_in[10];
    const float* b13  = (const float*)d_in[11];
    const float* cw1  = (const float*)d_in[12];
    const float* g    = (const float*)d_in[13];
    const float* be   = (const float*)d_in[14];
    const float* w21s = (const float*)d_in[15];
    const float* w21n = (const float*)d_in[16];
    const float* b21  = (const float*)d_in[17];
    const float* w22  = (const float*)d_in[18];
    const float* b22  = (const float*)d_in[19];
    const float* w23  = (const float*)d_in[20];
    const float* a23l = (const float*)d_in[21];
    const float* a23r = (const float*)d_in[22];
    const float* b23  = (const float*)d_in[23];
    const float* cw2  = (const float*)d_in[24];

    const int N = in_sizes[0] / DIN;
    const int E = in_sizes[1];

    char* ws = (char*)d_ws;
    size_t off = 0;
    auto alloc = [&](size_t bytes) { size_t o = off; off += (bytes + 255) & ~(size_t)255; return o; };
    u16*   Xb     = (u16*)(ws + alloc((size_t)N * 128 * 2));
    u8*    Xq     = (u8*)(ws + alloc((size_t)(N + 1) * 128));     // +1 zero row
    u16*   AG     = (u16*)(ws + alloc((size_t)N * 384 * 2));
    u16*   hpre   = (u16*)(ws + alloc((size_t)N * 128 * 2));
    u16*   h      = (u16*)(ws + alloc((size_t)N * 128 * 2));
    u8*    h8     = (u8*)(ws + alloc((size_t)(N + 1) * 128));     // +1 zero row
    int*   col    = (int*)(ws + alloc((size_t)E * 4));
    u8*    wsrank = (u8*)(ws + alloc((size_t)E));
    int*   rowptrR = (int*)(ws + alloc((size_t)(NPAD + 1) * 4));
    int*   rowptrN = (int*)(ws + alloc((size_t)N * 4));
    int*   excl   = (int*)(ws + alloc((size_t)NPAD * 4));
    int*   bsum   = (int*)(ws + alloc(256 * 4));
    int*   perm   = (int*)(ws + alloc((size_t)NPAD * 4));
    float* ns     = (float*)(ws + alloc((size_t)N * 4));
    float2* elns  = (float2*)(ws + alloc((size_t)N * 8));
    float* er     = (float*)(ws + alloc((size_t)N * 4));
    u16*   Wf1    = (u16*)(ws + alloc((size_t)16 * 8 * 64 * 8 * 2));
    u16*   Wf2    = (u16*)(ws + alloc((size_t)16 * 3 * 64 * 8 * 2));
    float* bc1    = (float*)(ws + alloc(128 * 4));
    float* bc2    = (float*)(ws + alloc(40 * 4));
    float* vattn  = (float*)(ws + alloc(512 * 4));
    float* bnacc  = (float*)(ws + alloc(256 * 4));
    float* bnpart = (float*)(ws + alloc((size_t)((N + 63) / 64) * 256 * 4));

    // Overlays: partials (u8, 12.85 MB each) live only hist2->place2.
    u8* partialsS = (u8*)AG;
    u8* partialsD = (u8*)hpre;

    int eps = (E + NSTRIPE - 1) / NSTRIPE;
    int wb = (N * 64 + 255) / 256;
    int ab = NPAD / 16;                    // k_agg: 4 ranks/wave, 16 ranks/block
    int gb = (N + 63) / 64;
    int pb = NPAD / 256;

    // fused weight prep (Wf1 + Wf2 + attn + biases + zero rows)
    k_prep<<<(90856 + 255) / 256, 256, 0, stream>>>(
        w11s, w11n, w12, w13, b11, b12, b13, cw1,
        w21s, w21n, w22, w23, b21, b22, b23, cw2,
        a13l, a13r, a23l, a23r, Wf1, Wf2, bc1, bc2, vattn,
        (u32*)(Xq + (size_t)N * 128), (u32*)(h8 + (size_t)N * 128));

    // CSR build: u8 histogram (1 edge pass), prefix+degree-sort+rank-scan
    k_hist2<<<NSTRIPE, 512, 0, stream>>>(src, dst, partialsS, partialsD, wsrank, E, eps);
    k_pfx2<<<pb, 256, 0, stream>>>(partialsS, partialsD, excl, bsum, ns, perm, N);

    // cvt/dots + rank-ordered rowptr finalize, then placement
    k_cvt_dots<<<wb, 256, 0, stream>>>(x, vattn, vattn + 128, ns, excl, bsum, perm,
                                       Xb, Xq, elns, er, rowptrR, rowptrN, N, E, pb, NPAD);
    {
        dim3 pg(NSTRIPE, 4);
        k_place2<<<pg, 256, 0, stream>>>(src, dst, rowptrN, partialsD, wsrank, col, E, eps);
    }

    // ---- layer 1 ----
    k_agg<<<ab, 256, 0, stream>>>(Xq, rowptrR, col, elns, er, perm, AG, N, NPAD);
    k_gemm1<<<gb, 256, 0, stream>>>(Xb, AG, Wf1, bc1, hpre, bnpart, N);

    // BN partial reduce (parallel), then fused final+norm+logits
    k_bn_reduce<<<256, 256, 0, stream>>>(bnpart, bnacc, gb);
    k_bnorm_dots<<<wb, 256, 0, stream>>>(hpre, bnacc, g, be, vattn + 256, vattn + 384, ns,
                                         h, h8, elns, er, (float)N, N);

    // ---- layer 2 ----
    k_agg<<<ab, 256, 0, stream>>>(h8, rowptrR, col, elns, er, perm, AG, N, NPAD);
    k_gemm2_lsm<<<gb, 256, 0, stream>>>(h, AG, Wf2, bc2, (float*)d_out, N);
}

// Round 13
// 364.392 us; speedup vs baseline: 1.1149x; 1.0298x over previous
//
#include <hip/hip_runtime.h>
#include <hip/hip_bf16.h>
#include <math.h>

#define DIN 128
#define DH  128
#define DC  40

#define NSTRIPE 256
#define NPAD    50176          // padded node slots (196 * 256)
#define H8_WORDS (NPAD / 4)    // u8-packed histogram words = 12544

typedef unsigned short u16;
typedef unsigned int u32;
typedef unsigned char u8;
typedef __attribute__((ext_vector_type(2))) float f32x2;
typedef __attribute__((ext_vector_type(4))) float f32x4;
typedef __attribute__((ext_vector_type(8))) short bf16x8;

static __device__ __forceinline__ float bf2f(u16 u) {
    union { u32 i; float f; } v; v.i = ((u32)u) << 16; return v.f;
}
static __device__ __forceinline__ u16 f2bf(float f) {
    __hip_bfloat16 h = __float2bfloat16(f);
    union { __hip_bfloat16 h; u16 u; } v; v.h = h; return v.u;
}
static __device__ __forceinline__ u32 pack2bf(float a, float b) {
    return ((u32)f2bf(b) << 16) | (u32)f2bf(a);
}
// 1-inst packed f32->bf16 pair (lo = a, hi = b); RNE, matches __float2bfloat16
static __device__ __forceinline__ u32 cvtpk_bf16(float a, float b) {
    u32 r;
    asm("v_cvt_pk_bf16_f32 %0, %1, %2" : "=v"(r) : "v"(a), "v"(b));
    return r;
}

// ---------- fp8 e4m3fn helpers ----------
static __device__ __forceinline__ u8 f2fp8(float f) {
    u32 s = (__float_as_uint(f) >> 31) << 7;
    float a = fabsf(f);
    a = fminf(a, 448.f);
    if (a < 0.015625f) {
        int q = (int)rintf(a * 512.f);
        return (u8)(s | (u32)q);
    }
    u32 x = __float_as_uint(a);
    u32 lsb = (x >> 20) & 1;
    x += 0x0007FFFF + lsb;
    u32 e = (x >> 23) - 120;
    u32 m = (x >> 20) & 7;
    return (u8)(s | (e << 3) | m);
}

#if __has_builtin(__builtin_amdgcn_cvt_pk_f32_fp8)
template<bool HI>
static __device__ __forceinline__ f32x2 fp8pk(u32 w) {
    return __builtin_amdgcn_cvt_pk_f32_fp8((int)w, HI);
}
#else
static __device__ __forceinline__ float fp8dec1(u32 byte) {
    u32 s = (byte >> 7) & 1, em = byte & 0x7F;
    float v = __uint_as_float((s << 31) | (em << 20)) * 0x1p120f;
    return v;
}
template<bool HI>
static __device__ __forceinline__ f32x2 fp8pk(u32 w) {
    u32 b0 = HI ? ((w >> 16) & 0xff) : (w & 0xff);
    u32 b1 = HI ? ((w >> 24) & 0xff) : ((w >> 8) & 0xff);
    f32x2 r; r.x = fp8dec1(b0); r.y = fp8dec1(b1); return r;
}
#endif

// ---------- fused weight prep: w1 frags + w2 frags + attn dots + biases
// ---------- + zero rows of Xq/h8 (for guard-free k_agg) ----------
__global__ __launch_bounds__(256) void k_prep(
        const float* w11s, const float* w11n, const float* w12, const float* w13,
        const float* b11, const float* b12, const float* b13, const float* cw1,
        const float* w21s, const float* w21n, const float* w22, const float* w23,
        const float* b21, const float* b22, const float* b23, const float* cw2,
        const float* a13l, const float* a13r, const float* a23l, const float* a23r,
        u16* __restrict__ Wf1, u16* __restrict__ Wf2,
        float* __restrict__ bc1, float* __restrict__ bc2, float* __restrict__ vattn,
        u32* __restrict__ zq, u32* __restrict__ zh) {
    int i = blockIdx.x * 256 + threadIdx.x;
    float s1 = cw1[0] + cw1[1] + cw1[2];
    float u0 = cw1[0] / s1, u1 = cw1[1] / s1, u2 = cw1[2] / s1;
    float s2 = cw2[0] + cw2[1] + cw2[2];
    float q0 = cw2[0] / s2, q1 = cw2[1] / s2, q2 = cw2[2] / s2;
    if (i < 65536) {                                   // Wf1 frags
        int j = i & 7, lane = (i >> 3) & 63, nt = (i >> 9) & 7, kt = i >> 12;
        int k = kt * 32 + ((lane >> 4) << 3) + j;
        int n = nt * 16 + (lane & 15);
        float v;
        if (k < 128)      v = u0 * w11s[k * 128 + n];
        else if (k < 256) v = u0 * w11n[(k - 128) * 128 + n];
        else if (k < 384) v = u1 * w12[(k - 256) * 128 + n];
        else              v = u2 * w13[(k - 384) * 128 + n];
        Wf1[i] = f2bf(v);
    } else if (i < 90112) {                            // Wf2 frags
        int i2 = i - 65536;
        int j = i2 & 7;
        int l2 = i2 >> 3;
        int lane = l2 & 63;
        int t2 = l2 >> 6;
        int nt = t2 % 3, kt = t2 / 3;
        int k = kt * 32 + ((lane >> 4) << 3) + j;
        int n = nt * 16 + (lane & 15);
        float v = 0.f;
        if (n < 40) {
            if (k < 128)      v = q0 * w21s[k * 40 + n];
            else if (k < 256) v = q0 * w21n[(k - 128) * 40 + n];
            else if (k < 384) v = q1 * w22[(k - 256) * 40 + n];
            else              v = q2 * w23[(k - 384) * 40 + n];
        }
        Wf2[i2] = f2bf(v);
    } else if (i < 90624) {                            // attn dots
        int t = i - 90112;
        if (t < 128) {
            float s = 0; for (int j = 0; j < 128; ++j) s += w13[t * 128 + j] * a13l[j];
            vattn[t] = s;
        } else if (t < 256) {
            int r = t - 128; float s = 0; for (int j = 0; j < 128; ++j) s += w13[r * 128 + j] * a13r[j];
            vattn[t] = s;
        } else if (t < 384) {
            int r = t - 256; float s = 0; for (int j = 0; j < 40; ++j) s += w23[r * 40 + j] * a23l[j];
            vattn[t] = s;
        } else {
            int r = t - 384; float s = 0; for (int j = 0; j < 40; ++j) s += w23[r * 40 + j] * a23r[j];
            vattn[t] = s;
        }
    } else if (i < 90752) {                            // bc1
        int c = i - 90624;
        bc1[c] = u0 * b11[c] + u1 * b12[c] + u2 * b13[c];
    } else if (i < 90792) {                            // bc2
        int c = i - 90752;
        bc2[c] = q0 * b21[c] + q1 * b22[c] + q2 * b23[c];
    } else if (i < 90856) {                            // zero rows Xq[n], h8[n]
        int t = i - 90792;
        if (t < 32) zq[t] = 0u; else zh[t - 32] = 0u;
    }
}

// ---------- CSR build: single-chunk dual LDS histogram, ONE edge pass ----------
__global__ __launch_bounds__(512) void k_hist2(const int* __restrict__ src,
        const int* __restrict__ dst,
        u8* __restrict__ partialsS, u8* __restrict__ partialsD,
        u8* __restrict__ wsrank, int E, int eps) {
    __shared__ u32 histD[H8_WORDS];
    __shared__ u32 histS[H8_WORDS];
    int stripe = blockIdx.x;
    for (int i = threadIdx.x; i < H8_WORDS; i += 512) { histD[i] = 0; histS[i] = 0; }
    __syncthreads();
    int e0 = stripe * eps;
    int e1 = e0 + eps; if (e1 > E) e1 = E;
    for (int e = e0 + threadIdx.x; e < e1; e += 512) {
        int ks = src[e];
        int kd = dst[e];
        atomicAdd(&histS[ks >> 2], 1u << ((ks & 3) * 8));
        u32 old = atomicAdd(&histD[kd >> 2], 1u << ((kd & 3) * 8));
        wsrank[e] = (u8)((old >> ((kd & 3) * 8)) & 0xff);
    }
    __syncthreads();
    u32* prowS = (u32*)(partialsS + (size_t)stripe * NPAD);
    u32* prowD = (u32*)(partialsD + (size_t)stripe * NPAD);
    for (int i = threadIdx.x; i < H8_WORDS; i += 512) { prowD[i] = histD[i]; prowS[i] = histS[i]; }
}

// per-node: src totals -> ns; dst prefix in place (u8) -> indeg; fused block-scan
__global__ __launch_bounds__(256) void k_pfx2(const u8* __restrict__ partialsS,
        u8* __restrict__ partialsD,
        int* __restrict__ excl, int* __restrict__ bsum,
        float* __restrict__ ns, int n) {
    int node = blockIdx.x * 256 + threadIdx.x;
    int runS = 0;
    for (int s0 = 0; s0 < NSTRIPE; s0 += 16) {
        u8 c[16];
#pragma unroll
        for (int i = 0; i < 16; ++i) c[i] = partialsS[(size_t)(s0 + i) * NPAD + node];
#pragma unroll
        for (int i = 0; i < 16; ++i) runS += c[i];
    }
    int runD = 0;
    for (int s0 = 0; s0 < NSTRIPE; s0 += 16) {
        u8 c[16];
#pragma unroll
        for (int i = 0; i < 16; ++i) c[i] = partialsD[(size_t)(s0 + i) * NPAD + node];
#pragma unroll
        for (int i = 0; i < 16; ++i) {
            partialsD[(size_t)(s0 + i) * NPAD + node] = (u8)runD;
            runD += c[i];
        }
    }
    if (node < n) {
        int d = runS < 1 ? 1 : runS;
        ns[node] = rsqrtf((float)d);
    }
    __shared__ int sh[256];
    sh[threadIdx.x] = runD; __syncthreads();
    for (int o = 1; o < 256; o <<= 1) {
        int t = (threadIdx.x >= o) ? sh[threadIdx.x - o] : 0;
        __syncthreads(); sh[threadIdx.x] += t; __syncthreads();
    }
    excl[node] = sh[threadIdx.x] - runD;
    if (threadIdx.x == 255) bsum[blockIdx.x] = sh[255];
}

// atomic-free placement: rowptr + stripe-prefix (u8) + within-stripe rank (u8)
__global__ __launch_bounds__(256) void k_place2(const int* __restrict__ src,
        const int* __restrict__ dst, const int* __restrict__ rowptr,
        const u8* __restrict__ partials, const u8* __restrict__ wsrank,
        int* __restrict__ col, int E, int eps) {
    int stripe = blockIdx.x;
    const u8* prow = partials + (size_t)stripe * NPAD;
    int sub = (eps + 3) >> 2;
    int e0 = stripe * eps + blockIdx.y * sub;
    int e1 = e0 + sub;
    int cap = stripe * eps + eps; if (cap > E) cap = E;
    if (e1 > cap) e1 = cap;
    for (int e = e0 + threadIdx.x; e < e1; e += 256) {
        int d = dst[e];
        col[rowptr[d] + prow[d] + wsrank[e]] = src[e];
    }
}

// ---------- fused: f32 x -> bf16 Xb + fp8 Xq + logits + rowptr finalize ----------
__global__ __launch_bounds__(256) void k_cvt_dots(const float* __restrict__ X,
        const float* __restrict__ vl, const float* __restrict__ vr, const float* __restrict__ ns,
        const int* __restrict__ excl, const int* __restrict__ bsum,
        u16* __restrict__ Xb, u8* __restrict__ Xq,
        float2* __restrict__ elns, float* __restrict__ er,
        int* __restrict__ rowptr, int n, int E, int pb) {
    __shared__ int sh[256], shE[256];
    int t = threadIdx.x;
    int v = (t < pb) ? bsum[t] : 0;
    sh[t] = v; __syncthreads();
    for (int o = 1; o < 256; o <<= 1) {
        int u = (t >= o) ? sh[t - o] : 0;
        __syncthreads(); sh[t] += u; __syncthreads();
    }
    shE[t] = sh[t] - v;        // exclusive scan of block sums
    __syncthreads();
    if (blockIdx.x == 0 && t == 0) rowptr[n] = E;
    int w = (blockIdx.x * blockDim.x + t) >> 6;
    int lane = t & 63;
    if (w >= n) return;
    float2 xv = *(const float2*)&X[(size_t)w * 128 + lane * 2];
    *(u32*)&Xb[(size_t)w * 128 + lane * 2] = cvtpk_bf16(xv.x, xv.y);
    u16 q = (u16)f2fp8(xv.x) | ((u16)f2fp8(xv.y) << 8);
    *(u16*)&Xq[(size_t)w * 128 + lane * 2] = q;
    float2 a = *(const float2*)&vl[lane * 2];
    float2 b = *(const float2*)&vr[lane * 2];
    float dl = xv.x * a.x + xv.y * a.y;
    float dr = xv.x * b.x + xv.y * b.y;
    for (int off = 32; off; off >>= 1) {
        dl += __shfl_down(dl, off);
        dr += __shfl_down(dr, off);
    }
    if (lane == 0) {
        rowptr[w] = excl[w] + shE[w >> 8];
        elns[w] = make_float2(dl, ns[w]);
        er[w] = dr;
    }
}

// ---------- aggregation: 4 nodes/wave, one 16-lane group per node ----------
// Group g owns node w = wave*4+g end-to-end: header loads 16 edges (lane gl =
// edge), inner step broadcasts edge t from lane g*16+t so each lane keeps the
// COMPLETE sum of its 8 features -- epilogue needs no cross-group shuffles.
// Zero-row padding (s=n) makes degree variance across the 4 nodes branch-free.
__global__ __launch_bounds__(256) void k_agg(const u8* __restrict__ Xq,
        const int* __restrict__ rowptr, const int* __restrict__ colsrc,
        const float2* __restrict__ elns, const float* __restrict__ er,
        u16* __restrict__ AG, int n) {
    int wave = (blockIdx.x * blockDim.x + threadIdx.x) >> 6;
    int lane = threadIdx.x & 63;
    int g = lane >> 4, gl = lane & 15;
    int w = wave * 4 + g;
    bool act = (w < n);
    int beg = 0, end = 0;
    if (act) { beg = rowptr[w]; end = rowptr[w + 1]; }
    int k = end - beg;
    float erd = act ? er[w] : 0.f;
    int kmax = k;
    kmax = max(kmax, __shfl_xor(kmax, 16));
    kmax = max(kmax, __shfl_xor(kmax, 32));
    f32x2 aS2[4] = {}, aG2[4] = {}, aA2[4] = {};
    float ssum_l = 0.f;
    for (int c = 0; c < kmax; c += 16) {
        int cnt = k - c; cnt = cnt < 0 ? 0 : (cnt > 16 ? 16 : cnt);
        int s = n; float p = 0.f, nsl = 0.f;
        if (gl < cnt) {
            s = colsrc[beg + c + gl];
            float2 v = elns[s];
            float t = v.x + erd;
            t = t > 0.f ? t : 0.2f * t;            // leaky_relu 0.2
            p = __expf(t);
            nsl = v.y;
        }
        ssum_l += p;
        int cm = kmax - c; if (cm > 16) cm = 16;   // wave-uniform step bound
#pragma unroll 8
        for (int t = 0; t < cm; ++t) {
            int j = (g << 4) + t;                  // edge t of MY group
            int sj = __shfl(s, j);
            float pj = __shfl(p, j);
            float nsj = __shfl(nsl, j);
            uint2 xq = *(const uint2*)&Xq[(size_t)sj * 128 + gl * 8];
            f32x2 xv2[4] = {fp8pk<false>(xq.x), fp8pk<true>(xq.x),
                            fp8pk<false>(xq.y), fp8pk<true>(xq.y)};
            f32x2 ns2 = {nsj, nsj}, p2 = {pj, pj};
#pragma unroll
            for (int q = 0; q < 4; ++q) {
                aS2[q] += xv2[q];
                aG2[q] += ns2 * xv2[q];
                aA2[q] += p2 * xv2[q];
            }
        }
    }
    // softmax denom: reduce within the 16-lane group
    ssum_l += __shfl_xor(ssum_l, 1);
    ssum_l += __shfl_xor(ssum_l, 2);
    ssum_l += __shfl_xor(ssum_l, 4);
    ssum_l += __shfl_xor(ssum_l, 8);
    if (!act) return;
    int kc = k < 1 ? 1 : k;
    float invk = 1.f / (float)kc;
    float ndd = rsqrtf((float)kc);
    float gi = 1.f / fmaxf(ssum_l, 1e-9f);
    u16* row = AG + (size_t)w * 384;
    uint2 oS = make_uint2(pack2bf(aS2[0][0] * invk, aS2[0][1] * invk),
                          pack2bf(aS2[1][0] * invk, aS2[1][1] * invk));
    uint2 oS2 = make_uint2(pack2bf(aS2[2][0] * invk, aS2[2][1] * invk),
                           pack2bf(aS2[3][0] * invk, aS2[3][1] * invk));
    *(uint4*)&row[gl * 8] = make_uint4(oS.x, oS.y, oS2.x, oS2.y);
    uint2 oG = make_uint2(pack2bf(aG2[0][0] * ndd, aG2[0][1] * ndd),
                          pack2bf(aG2[1][0] * ndd, aG2[1][1] * ndd));
    uint2 oG2 = make_uint2(pack2bf(aG2[2][0] * ndd, aG2[2][1] * ndd),
                           pack2bf(aG2[3][0] * ndd, aG2[3][1] * ndd));
    *(uint4*)&row[128 + gl * 8] = make_uint4(oG.x, oG.y, oG2.x, oG2.y);
    uint2 oA = make_uint2(pack2bf(aA2[0][0] * gi, aA2[0][1] * gi),
                          pack2bf(aA2[1][0] * gi, aA2[1][1] * gi));
    uint2 oA2 = make_uint2(pack2bf(aA2[2][0] * gi, aA2[2][1] * gi),
                           pack2bf(aA2[3][0] * gi, aA2[3][1] * gi));
    *(uint4*)&row[256 + gl * 8] = make_uint4(oA.x, oA.y, oA2.x, oA2.y);
}

// ---------- MFMA GEMM layer1 + per-block BN column partials (no atomics) ----------
__global__ __launch_bounds__(256) void k_gemm1(const u16* __restrict__ Xb,
        const u16* __restrict__ AG, const u16* __restrict__ Wf,
        const float* __restrict__ bias, u16* __restrict__ C,
        float* __restrict__ bnpart, int M) {
    const int NT = 8;
    int wave = threadIdx.x >> 6;
    int lane = threadIdx.x & 63;
    int m0 = blockIdx.x * 64 + wave * 16;
    int arow = m0 + (lane & 15);
    if (arow >= M) arow = M - 1;
    int kq = lane >> 4;
    f32x4 acc[NT];
#pragma unroll
    for (int t = 0; t < NT; ++t) acc[t] = (f32x4){0.f, 0.f, 0.f, 0.f};
#pragma unroll
    for (int kt = 0; kt < 16; ++kt) {
        int k0 = kt * 32 + kq * 8;
        bf16x8 a;
        if (k0 < 128) a = *(const bf16x8*)&Xb[(size_t)arow * 128 + k0];
        else          a = *(const bf16x8*)&AG[(size_t)arow * 384 + (k0 - 128)];
        const u16* wb = Wf + ((size_t)kt * NT) * 512 + lane * 8;
#pragma unroll
        for (int t = 0; t < NT; ++t) {
            bf16x8 b = *(const bf16x8*)&wb[(size_t)t * 512];
            acc[t] = __builtin_amdgcn_mfma_f32_16x16x32_bf16(a, b, acc[t], 0, 0, 0);
        }
    }
    __shared__ float sS[128], sQ[128];
    if (threadIdx.x < 128) { sS[threadIdx.x] = 0.f; sQ[threadIdx.x] = 0.f; }
    __syncthreads();
    int ccol = lane & 15;
    int rbase = m0 + kq * 4;
#pragma unroll
    for (int t = 0; t < NT; ++t) {
        int col = t * 16 + ccol;
        float bv = bias[col];
        float cs = 0.f, cq = 0.f;
#pragma unroll
        for (int r = 0; r < 4; ++r) {
            int rr = rbase + r;
            float v = acc[t][r] + bv;
            if (rr < M) {
                C[(size_t)rr * 128 + col] = f2bf(v);
                cs += v; cq += v * v;
            }
        }
        cs += __shfl_xor(cs, 16); cs += __shfl_xor(cs, 32);
        cq += __shfl_xor(cq, 16); cq += __shfl_xor(cq, 32);
        if (kq == 0) {
            atomicAdd(&sS[col], cs);
            atomicAdd(&sQ[col], cq);
        }
    }
    __syncthreads();
    if (threadIdx.x < 128) {
        bnpart[(size_t)blockIdx.x * 256 + threadIdx.x] = sS[threadIdx.x];
        bnpart[(size_t)blockIdx.x * 256 + 128 + threadIdx.x] = sQ[threadIdx.x];
    }
}

// ---------- reduce per-block BN partials -> bnacc[256] (parallel: 256 blocks) ----------
__global__ __launch_bounds__(256) void k_bn_reduce(const float* __restrict__ bnpart,
                                                   float* __restrict__ bnacc, int nb) {
    int c = blockIdx.x;                     // one column per block
    float s = 0.f;
    for (int r = threadIdx.x; r < nb; r += 256)
        s += bnpart[(size_t)r * 256 + c];
    for (int o = 32; o; o >>= 1) s += __shfl_xor(s, o);
    __shared__ float sw[4];
    if ((threadIdx.x & 63) == 0) sw[threadIdx.x >> 6] = s;
    __syncthreads();
    if (threadIdx.x == 0) bnacc[c] = sw[0] + sw[1] + sw[2] + sw[3];
}

// ---------- MFMA GEMM layer2 (N=40) fused with log_softmax, writes f32 out ----------
__global__ __launch_bounds__(256) void k_gemm2_lsm(const u16* __restrict__ Xb,
        const u16* __restrict__ AG, const u16* __restrict__ Wf,
        const float* __restrict__ bias, float* __restrict__ out, int M) {
    const int NT = 3;
    int wave = threadIdx.x >> 6;
    int lane = threadIdx.x & 63;
    int m0 = blockIdx.x * 64 + wave * 16;
    int arow = m0 + (lane & 15);
    if (arow >= M) arow = M - 1;
    int kq = lane >> 4;
    f32x4 acc[NT];
#pragma unroll
    for (int t = 0; t < NT; ++t) acc[t] = (f32x4){0.f, 0.f, 0.f, 0.f};
#pragma unroll
    for (int kt = 0; kt < 16; ++kt) {
        int k0 = kt * 32 + kq * 8;
        bf16x8 a;
        if (k0 < 128) a = *(const bf16x8*)&Xb[(size_t)arow * 128 + k0];
        else          a = *(const bf16x8*)&AG[(size_t)arow * 384 + (k0 - 128)];
        const u16* wb = Wf + ((size_t)kt * NT) * 512 + lane * 8;
#pragma unroll
        for (int t = 0; t < NT; ++t) {
            bf16x8 b = *(const bf16x8*)&wb[(size_t)t * 512];
            acc[t] = __builtin_amdgcn_mfma_f32_16x16x32_bf16(a, b, acc[t], 0, 0, 0);
        }
    }
    int ccol = lane & 15;
    int rbase = m0 + kq * 4;
    bool valid[NT];
    float bv[NT];
#pragma unroll
    for (int t = 0; t < NT; ++t) {
        int col = t * 16 + ccol;
        valid[t] = (col < 40);
        bv[t] = valid[t] ? bias[col] : 0.f;
    }
#pragma unroll
    for (int r = 0; r < 4; ++r) {
        float v[NT];
#pragma unroll
        for (int t = 0; t < NT; ++t) v[t] = valid[t] ? (acc[t][r] + bv[t]) : -INFINITY;
        float mx = fmaxf(fmaxf(v[0], v[1]), v[2]);
        for (int o = 1; o < 16; o <<= 1) mx = fmaxf(mx, __shfl_xor(mx, o));
        float se = 0.f;
#pragma unroll
        for (int t = 0; t < NT; ++t) se += valid[t] ? __expf(v[t] - mx) : 0.f;
        for (int o = 1; o < 16; o <<= 1) se += __shfl_xor(se, o);
        float lse = mx + logf(se);
        int rr = rbase + r;
        if (rr < M) {
#pragma unroll
            for (int t = 0; t < NT; ++t) {
                int col = t * 16 + ccol;
                if (valid[t]) out[(size_t)rr * 40 + col] = v[t] - lse;
            }
        }
    }
}

// ---------- fused: BN-final + BN+ReLU -> bf16 h + fp8 h8 + layer-2 logits ----------
__global__ __launch_bounds__(256) void k_bnorm_dots(const u16* __restrict__ Hp,
        const float* __restrict__ bnacc, const float* __restrict__ g, const float* __restrict__ be,
        const float* __restrict__ vl, const float* __restrict__ vr,
        const float* __restrict__ ns,
        u16* __restrict__ H, u8* __restrict__ H8,
        float2* __restrict__ elns, float* __restrict__ er, float Nf, int n) {
    int w = (blockIdx.x * blockDim.x + threadIdx.x) >> 6;
    int lane = threadIdx.x & 63;
    if (w >= n) return;
    int c0 = lane * 2, c1 = lane * 2 + 1;
    float mu0 = bnacc[c0] / Nf, mu1 = bnacc[c1] / Nf;
    float var0 = bnacc[128 + c0] / Nf - mu0 * mu0;
    float var1 = bnacc[128 + c1] / Nf - mu1 * mu1;
    float sc0 = g[c0] * rsqrtf(var0 + 1e-5f);
    float sc1 = g[c1] * rsqrtf(var1 + 1e-5f);
    float sh0 = be[c0] - mu0 * sc0;
    float sh1 = be[c1] - mu1 * sc1;
    u32 hu = *(const u32*)&Hp[(size_t)w * 128 + lane * 2];
    float vx = bf2f((u16)hu), vy = bf2f((u16)(hu >> 16));
    float h0 = fmaxf(vx * sc0 + sh0, 0.f);
    float h1 = fmaxf(vy * sc1 + sh1, 0.f);
    *(u32*)&H[(size_t)w * 128 + lane * 2] = cvtpk_bf16(h0, h1);
    u16 q = (u16)f2fp8(h0) | ((u16)f2fp8(h1) << 8);
    *(u16*)&H8[(size_t)w * 128 + lane * 2] = q;
    float2 a = *(const float2*)&vl[lane * 2];
    float2 b = *(const float2*)&vr[lane * 2];
    float dl = h0 * a.x + h1 * a.y;
    float dr = h0 * b.x + h1 * b.y;
    for (int off = 32; off; off >>= 1) {
        dl += __shfl_down(dl, off);
        dr += __shfl_down(dr, off);
    }
    if (lane == 0) { elns[w] = make_float2(dl, ns[w]); er[w] = dr; }
}

extern "C" void kernel_launch(void* const* d_in, const int* in_sizes, int n_in,
                              void* d_out, int out_size, void* d_ws, size_t ws_size,
                              hipStream_t stream) {
    const float* x    = (const float*)d_in[0];
    const int*   src  = (const int*)d_in[1];
    const int*   dst  = (const int*)d_in[2];
    const float* w11s = (const float*)d_in[3];
    const float* w11n = (const float*)d_in[4];
    const float* b11  = (const float*)d_in[5];
    const float* w12  = (const float*)d_in[6];
    const float* b12  = (const float*)d_in[7];
    const float* w13  = (const float*)d_in[8];
    const float* a13l = (const float*)d_in[9];
    const float* a13r = (const float*)d_in[10];
    const float* b13  = (const float*)d_in[11];
    const float* cw1  = (const float*)d_in[12];
    const float* g    = (const float*)d_in[13];
    const float* be   = (const float*)d_in[14];
    const float* w21s = (const float*)d_in[15];
    const float* w21n = (const float*)d_in[16];
    const float* b21  = (const float*)d_in[17];
    const float* w22  = (const float*)d_in[18];
    const float* b22  = (const float*)d_in[19];
    const float* w23  = (const float*)d_in[20];
    const float* a23l = (const float*)d_in[21];
    const float* a23r = (const float*)d_in[22];
    const float* b23  = (const float*)d_in[23];
    const float* cw2  = (const float*)d_in[24];

    const int N = in_sizes[0] / DIN;
    const int E = in_sizes[1];

    char* ws = (char*)d_ws;
    size_t off = 0;
    auto alloc = [&](size_t bytes) { size_t o = off; off += (bytes + 255) & ~(size_t)255; return o; };
    u16*   Xb     = (u16*)(ws + alloc((size_t)N * 128 * 2));
    u8*    Xq     = (u8*)(ws + alloc((size_t)(N + 1) * 128));     // +1 zero row
    u16*   AG     = (u16*)(ws + alloc((size_t)N * 384 * 2));
    u16*   hpre   = (u16*)(ws + alloc((size_t)N * 128 * 2));
    u16*   h      = (u16*)(ws + alloc((size_t)N * 128 * 2));
    u8*    h8     = (u8*)(ws + alloc((size_t)(N + 1) * 128));     // +1 zero row
    int*   col    = (int*)(ws + alloc((size_t)E * 4));
    u8*    wsrank = (u8*)(ws + alloc((size_t)E));
    int*   rowptr = (int*)(ws + alloc((size_t)(N + 1) * 4));
    int*   excl   = (int*)(ws + alloc((size_t)NPAD * 4));
    int*   bsum   = (int*)(ws + alloc(256 * 4));
    float* ns     = (float*)(ws + alloc((size_t)N * 4));
    float2* elns  = (float2*)(ws + alloc((size_t)N * 8));
    float* er     = (float*)(ws + alloc((size_t)N * 4));
    u16*   Wf1    = (u16*)(ws + alloc((size_t)16 * 8 * 64 * 8 * 2));
    u16*   Wf2    = (u16*)(ws + alloc((size_t)16 * 3 * 64 * 8 * 2));
    float* bc1    = (float*)(ws + alloc(128 * 4));
    float* bc2    = (float*)(ws + alloc(40 * 4));
    float* vattn  = (float*)(ws + alloc(512 * 4));
    float* bnacc  = (float*)(ws + alloc(256 * 4));
    float* bnpart = (float*)(ws + alloc((size_t)((N + 63) / 64) * 256 * 4));

    // Overlays: partials (u8, 12.85 MB each) live only hist2->place2.
    u8* partialsS = (u8*)AG;
    u8* partialsD = (u8*)hpre;

    int eps = (E + NSTRIPE - 1) / NSTRIPE;
    int wb = (N * 64 + 255) / 256;
    int ab = (N + 15) / 16;                // k_agg: 4 nodes/wave, 16/block
    int gb = (N + 63) / 64;
    int pb = NPAD / 256;

    // fused weight prep (Wf1 + Wf2 + attn + biases + zero rows)
    k_prep<<<(90856 + 255) / 256, 256, 0, stream>>>(
        w11s, w11n, w12, w13, b11, b12, b13, cw1,
        w21s, w21n, w22, w23, b21, b22, b23, cw2,
        a13l, a13r, a23l, a23r, Wf1, Wf2, bc1, bc2, vattn,
        (u32*)(Xq + (size_t)N * 128), (u32*)(h8 + (size_t)N * 128));

    // CSR build: single-chunk u8 histogram (1 edge pass), prefix+scan
    k_hist2<<<NSTRIPE, 512, 0, stream>>>(src, dst, partialsS, partialsD, wsrank, E, eps);
    k_pfx2<<<pb, 256, 0, stream>>>(partialsS, partialsD, excl, bsum, ns, N);

    // cvt/dots + rowptr finalize (absorbs scan2+scan3), then placement
    k_cvt_dots<<<wb, 256, 0, stream>>>(x, vattn, vattn + 128, ns, excl, bsum,
                                       Xb, Xq, elns, er, rowptr, N, E, pb);
    {
        dim3 pg(NSTRIPE, 4);
        k_place2<<<pg, 256, 0, stream>>>(src, dst, rowptr, partialsD, wsrank, col, E, eps);
    }

    // ---- layer 1 ----
    k_agg<<<ab, 256, 0, stream>>>(Xq, rowptr, col, elns, er, AG, N);
    k_gemm1<<<gb, 256, 0, stream>>>(Xb, AG, Wf1, bc1, hpre, bnpart, N);

    // BN partial reduce (parallel), then fused final+norm+logits
    k_bn_reduce<<<256, 256, 0, stream>>>(bnpart, bnacc, gb);
    k_bnorm_dots<<<wb, 256, 0, stream>>>(hpre, bnacc, g, be, vattn + 256, vattn + 384, ns,
                                         h, h8, elns, er, (float)N, N);

    // ---- layer 2 ----
    k_agg<<<ab, 256, 0, stream>>>(h8, rowptr, col, elns, er, AG, N);
    k_gemm2_lsm<<<gb, 256, 0, stream>>>(h, AG, Wf2, bc2, (float*)d_out, N);
}